// Round 3
// baseline (228.768 us; speedup 1.0000x reference)
//
#include <hip/hip_runtime.h>
#include <math.h>

#define N_PTS 100000
#define P_PROP 256
#define R_FEAT 256
#define NCLS 21          // C + 1
#define NSEG 32          // segments; xyz window 37.5KB + fW window 300KB << 4 MiB XCD-L2
#define SEG_LEN (N_PTS / NSEG)   // 3125 exactly
#define LIST_MAX 3136    // >= SEG_LEN, multiple of 64
#define FW_STRIDE 48     // padded bf16 channels per row: 21 cls | 21 obj | 6 pad = 96B = 2 lines
#define ACC_STRIDE 44    // 42 channel sums + 1 count + 1 pad
#define MTILE 128        // rows per featw block (4 waves x 2 x 16-row MFMA tiles)
#define FEATW_BLOCKS ((N_PTS + MTILE - 1) / MTILE)   // 782
#define NFRAG (3 * 8 * 64)   // B fragments: 3 N-tiles x 8 K-steps x 64 lanes

typedef unsigned short u16t;
typedef unsigned int u32t;
typedef __attribute__((ext_vector_type(8))) short short8;   // 8 bf16 (4 VGPRs)
typedef __attribute__((ext_vector_type(4))) float f32x4;    // MFMA accumulator

__device__ __forceinline__ u16t f2bf_rne(float x) {
    u32t u = __float_as_uint(x);
    u += 0x7fffu + ((u >> 16) & 1u);
    return (u16t)(u >> 16);
}
__device__ __forceinline__ float bf2f(u16t v) {
    return __uint_as_float(((u32t)v) << 16);
}

// ---------------- Kernel P: build pre-swizzled bf16 B-frags + zero gacc ----
// One block. B = [Wc | Wo | 0pad] as 48 cols x 256 k, laid out as 1536
// 16B fragments indexed (ntile*8 + kstep)*64 + lane, so featw's K-loop reads
// each B operand with one ds_read_b128 after a trivial coalesced LDS copy.
// (Round-2 lesson: every featw block redoing this scatter+convert was the
// dominant cost of the MFMA kernel.)
__global__ __launch_bounds__(256) void prep_kernel(
    const float* __restrict__ Wc,      // (R,21)
    const float* __restrict__ Wo,      // (R,21)
    u16t* __restrict__ bfrag,          // (1536*8) bf16 = 24576 B
    float* __restrict__ gacc)          // (P,44) zeroed
{
    const int t = threadIdx.x;
    for (int i = t; i < P_PROP * ACC_STRIDE; i += 256) gacc[i] = 0.0f;

    for (int idx = t; idx < NFRAG; idx += 256) {
        const int n   = idx >> 9;         // N-tile 0..2
        const int rem = idx & 511;
        const int kk  = rem >> 6;         // K-step 0..7
        const int l   = rem & 63;         // lane
        const int krow = kk * 32 + (l >> 4) * 8;
        const int c    = n * 16 + (l & 15);
        u32t w[4];
#pragma unroll
        for (int jj = 0; jj < 4; ++jj) {
            const int k0 = krow + 2 * jj;
            float v0 = 0.0f, v1 = 0.0f;
            if (c < NCLS) {
                v0 = Wc[k0 * NCLS + c];
                v1 = Wc[(k0 + 1) * NCLS + c];
            } else if (c < 2 * NCLS) {
                v0 = Wo[k0 * NCLS + (c - NCLS)];
                v1 = Wo[(k0 + 1) * NCLS + (c - NCLS)];
            }
            w[jj] = (u32t)f2bf_rne(v0) | ((u32t)f2bf_rne(v1) << 16);
        }
        *(uint4*)(&bfrag[idx * 8]) = make_uint4(w[0], w[1], w[2], w[3]);
    }
}

// ---------------- Kernel 0: fW = feats @ [Wc | Wo] via bf16 MFMA -----------
// (sum_i feats_i) @ W == sum_i (feats_i @ W). 100000x256 @ 256x48 with
// mfma_f32_16x16x32_bf16. Block = 4 waves x 2 M-tiles of 16 rows = 128 rows.
// B-frags copied LDS-linearly from the prep image (6 uint4/thread), then the
// K-loop is pure {2 float4 A-loads + pack, 3 ds_read_b128, 3 MFMA} x 2 m.
// Accumulators are 6 named f32x4 (round-1 failure: indexable acc -> scratch).
// Fragment layouts (verified passing in round 2): A lane l: row=l&15,
// k=(l>>4)*8+j; B lane l: col=l&15, same k; D: col=lane&15, row=(lane>>4)*4+reg.
__global__ __launch_bounds__(256) void featw_kernel(
    const float* __restrict__ feats,   // (N,R)
    const u16t* __restrict__ bfrag,    // prep image, 24576 B
    u16t* __restrict__ fwb)            // (N,48) bf16
{
    const int t = threadIdx.x;

    __shared__ u16t bB[NFRAG * 8];     // 24 KiB

    // coalesced copy of the fragment image
#pragma unroll
    for (int i = 0; i < 6; ++i)
        ((uint4*)bB)[t + i * 256] = ((const uint4*)bfrag)[t + i * 256];
    __syncthreads();

    const int wv = t >> 6;
    const int l  = t & 63;
    const int rowbase = blockIdx.x * MTILE + wv * 32;

    const int r0 = rowbase + (l & 15);
    const int r1 = r0 + 16;
    const int r0c = r0 < N_PTS ? r0 : N_PTS - 1;
    const int r1c = r1 < N_PTS ? r1 : N_PTS - 1;
    const float* __restrict__ a0p = feats + (size_t)r0c * R_FEAT + (l >> 4) * 8;
    const float* __restrict__ a1p = feats + (size_t)r1c * R_FEAT + (l >> 4) * 8;

    f32x4 c00 = {0.f,0.f,0.f,0.f}, c01 = {0.f,0.f,0.f,0.f}, c02 = {0.f,0.f,0.f,0.f};
    f32x4 c10 = {0.f,0.f,0.f,0.f}, c11 = {0.f,0.f,0.f,0.f}, c12 = {0.f,0.f,0.f,0.f};

#pragma unroll
    for (int kk = 0; kk < 8; ++kk) {
        const short8 b0 = *(const short8*)(&bB[((0 * 8 + kk) * 64 + l) * 8]);
        const short8 b1 = *(const short8*)(&bB[((1 * 8 + kk) * 64 + l) * 8]);
        const short8 b2 = *(const short8*)(&bB[((2 * 8 + kk) * 64 + l) * 8]);

        const float4 x0 = *(const float4*)(a0p + kk * 32);
        const float4 x1 = *(const float4*)(a0p + kk * 32 + 4);
        union { u32t u[4]; short8 s; } af0;
        af0.u[0] = (u32t)f2bf_rne(x0.x) | ((u32t)f2bf_rne(x0.y) << 16);
        af0.u[1] = (u32t)f2bf_rne(x0.z) | ((u32t)f2bf_rne(x0.w) << 16);
        af0.u[2] = (u32t)f2bf_rne(x1.x) | ((u32t)f2bf_rne(x1.y) << 16);
        af0.u[3] = (u32t)f2bf_rne(x1.z) | ((u32t)f2bf_rne(x1.w) << 16);
        c00 = __builtin_amdgcn_mfma_f32_16x16x32_bf16(af0.s, b0, c00, 0, 0, 0);
        c01 = __builtin_amdgcn_mfma_f32_16x16x32_bf16(af0.s, b1, c01, 0, 0, 0);
        c02 = __builtin_amdgcn_mfma_f32_16x16x32_bf16(af0.s, b2, c02, 0, 0, 0);

        const float4 y0 = *(const float4*)(a1p + kk * 32);
        const float4 y1 = *(const float4*)(a1p + kk * 32 + 4);
        union { u32t u[4]; short8 s; } af1;
        af1.u[0] = (u32t)f2bf_rne(y0.x) | ((u32t)f2bf_rne(y0.y) << 16);
        af1.u[1] = (u32t)f2bf_rne(y0.z) | ((u32t)f2bf_rne(y0.w) << 16);
        af1.u[2] = (u32t)f2bf_rne(y1.x) | ((u32t)f2bf_rne(y1.y) << 16);
        af1.u[3] = (u32t)f2bf_rne(y1.z) | ((u32t)f2bf_rne(y1.w) << 16);
        c10 = __builtin_amdgcn_mfma_f32_16x16x32_bf16(af1.s, b0, c10, 0, 0, 0);
        c11 = __builtin_amdgcn_mfma_f32_16x16x32_bf16(af1.s, b1, c11, 0, 0, 0);
        c12 = __builtin_amdgcn_mfma_f32_16x16x32_bf16(af1.s, b2, c12, 0, 0, 0);
    }

    // ---- epilogue: D col = lane&15, row = (lane>>4)*4 + j; cols 42..47 pad
    const int ocol = l & 15;
    const int or0  = rowbase + (l >> 4) * 4;
#pragma unroll
    for (int j = 0; j < 4; ++j) {
        const int ra = or0 + j;
        if (ra < N_PTS) {
            u16t* __restrict__ orow = fwb + (size_t)ra * FW_STRIDE;
            orow[ocol]      = f2bf_rne(c00[j]);
            orow[ocol + 16] = f2bf_rne(c01[j]);
            orow[ocol + 32] = f2bf_rne(c02[j]);
        }
        const int rb = or0 + 16 + j;
        if (rb < N_PTS) {
            u16t* __restrict__ orow = fwb + (size_t)rb * FW_STRIDE;
            orow[ocol]      = f2bf_rne(c10[j]);
            orow[ocol + 16] = f2bf_rne(c11[j]);
            orow[ocol + 32] = f2bf_rne(c12[j]);
        }
    }
}

// ---------------- Kernel 1: masked per-segment sums of fW, atomic combine --
// grid = 8192 blocks, XCD-swizzled: bid = q*2048 + p*8 + x, s = q*8 + x.
// Mask+compact pass identical to the proven kernel. Gather: lane c (<24)
// owns channels 2c,2c+1 via one dword load per row (96B rows = exactly 2
// lines); 8 rows in flight per wave. Cross-wave LDS reduce, then 42
// atomicAdds/block into gacc (32-way contention per address).
__global__ __launch_bounds__(256) void roi_partial_kernel(
    const float* __restrict__ proposals,   // (P,6)
    const float* __restrict__ xyz,         // (N,3)
    const u16t* __restrict__ fwb,          // (N,48) bf16
    float* __restrict__ gacc)              // (P,44)
{
    const int bid = blockIdx.x;
    const int x = bid & 7;
    const int p = (bid >> 3) & (P_PROP - 1);
    const int q = bid >> 11;
    const int s = q * 8 + x;

    const int t = threadIdx.x;
    const int wave = t >> 6;
    const int lane = t & 63;

    const float cx = proposals[p * 6 + 0];
    const float cy = proposals[p * 6 + 1];
    const float cz = proposals[p * 6 + 2];
    const float hx = proposals[p * 6 + 3] * 0.5f;
    const float hy = proposals[p * 6 + 4] * 0.5f;
    const float hz = proposals[p * 6 + 5] * 0.5f;
    const float lox = cx - hx, hix = cx + hx;
    const float loy = cy - hy, hiy = cy + hy;
    const float loz = cz - hz, hiz = cz + hz;

    __shared__ int list[LIST_MAX];
    __shared__ float red[4][48];
    __shared__ int cnt;

    if (t == 0) cnt = 0;
    __syncthreads();

    const int n0 = s * SEG_LEN;
    const int n1 = n0 + SEG_LEN;

    // ---- mask + compact (single pass over the segment) ----
    for (int i = n0 + t; i < n1; i += 256) {
        const float xx = xyz[i * 3 + 0];
        const float yy = xyz[i * 3 + 1];
        const float zz = xyz[i * 3 + 2];
        const bool in = (xx >= lox) & (xx <= hix) &
                        (yy >= loy) & (yy <= hiy) &
                        (zz >= loz) & (zz <= hiz);
        const unsigned long long b = __ballot(in);
        const int prefix = __popcll(b & ((1ull << lane) - 1ull));
        const int nb = __popcll(b);
        int baseoff = 0;
        if (lane == 0 && nb) baseoff = atomicAdd(&cnt, nb);
        baseoff = __shfl(baseoff, 0, 64);
        if (in) list[baseoff + prefix] = i;
    }
    __syncthreads();

    const int m = cnt;

    // ---- gather: lane = dword-channel pair, wave-strided rows, 8 in flight
    if (lane < FW_STRIDE / 2) {
        const u32t* __restrict__ fw32 = (const u32t*)fwb;
        float sx = 0.0f, sy = 0.0f;
        int j = wave;
        for (; j + 28 < m; j += 32) {
            int r[8];
#pragma unroll
            for (int u = 0; u < 8; ++u) r[u] = list[j + 4 * u];
            u32t f[8];
#pragma unroll
            for (int u = 0; u < 8; ++u)
                f[u] = fw32[(size_t)r[u] * (FW_STRIDE / 2) + lane];
#pragma unroll
            for (int u = 0; u < 8; ++u) {
                sx += __uint_as_float(f[u] << 16);
                sy += __uint_as_float(f[u] & 0xffff0000u);
            }
        }
        for (; j < m; j += 4) {
            const u32t f = fw32[(size_t)list[j] * (FW_STRIDE / 2) + lane];
            sx += __uint_as_float(f << 16);
            sy += __uint_as_float(f & 0xffff0000u);
        }
        red[wave][lane * 2]     = sx;
        red[wave][lane * 2 + 1] = sy;
    }
    __syncthreads();

    if (t < 2 * NCLS) {
        const float v = red[0][t] + red[1][t] + red[2][t] + red[3][t];
        atomicAdd(&gacc[p * ACC_STRIDE + t], v);
    }
    if (t == 2 * NCLS) {
        atomicAdd(&gacc[p * ACC_STRIDE + 42], (float)m);
    }
}

// ---------------- Kernel 2: logits from gacc + softmaxes + product --------
// single block, 256 threads; thread t = proposal t. Reads its 176B gacc row,
// forms logits = sums/max(cnt,1) + bias, then the proven softmax structure:
// row softmax (cls) in registers, column softmax (obj) via 8x32 LDS groups.
__global__ __launch_bounds__(256) void softmax_mul_kernel(
    const float* __restrict__ gacc,        // (P,44)
    const float* __restrict__ bc,          // (21)
    const float* __restrict__ bo,          // (21)
    float* __restrict__ out)               // (P,21)
{
    const int t = threadIdx.x;
    const int cc = t & 31;
    const int g = t >> 5;

    __shared__ float objl[P_PROP][NCLS];
    __shared__ float red[8][32];
    __shared__ float colmax[32];
    __shared__ float colsum[32];

    float4 vv[11];
    const float4* __restrict__ rowp = (const float4*)(gacc + t * ACC_STRIDE);
#pragma unroll
    for (int j = 0; j < 11; ++j) vv[j] = rowp[j];
    const float* v = (const float*)vv;

    const float cntv = fmaxf(v[42], 1.0f);
    const float rinv = 1.0f / cntv;

    float cl[NCLS], ob[NCLS];
#pragma unroll
    for (int c = 0; c < NCLS; ++c) {
        cl[c] = v[c] * rinv + bc[c];
        ob[c] = v[NCLS + c] * rinv + bo[c];
        objl[t][c] = ob[c];
    }
    __syncthreads();

    // column max (over proposals), 8 groups of 32
    float m = -INFINITY;
    if (cc < NCLS) {
        const int p0 = g * 32;
        for (int p = p0; p < p0 + 32; ++p) m = fmaxf(m, objl[p][cc]);
    }
    red[g][cc] = m;
    __syncthreads();
    if (t < NCLS) {
        float mm = red[0][t];
#pragma unroll
        for (int gg = 1; gg < 8; ++gg) mm = fmaxf(mm, red[gg][t]);
        colmax[t] = mm;
    }
    __syncthreads();

    // column sum of exp
    float sc = 0.0f;
    if (cc < NCLS) {
        const float mm = colmax[cc];
        const int p0 = g * 32;
        for (int p = p0; p < p0 + 32; ++p) sc += expf(objl[p][cc] - mm);
    }
    red[g][cc] = sc;
    __syncthreads();
    if (t < NCLS) {
        float ss = red[0][t];
#pragma unroll
        for (int gg = 1; gg < 8; ++gg) ss += red[gg][t];
        colsum[t] = ss;
    }

    // row softmax (cls) in registers meanwhile
    float rm = cl[0];
#pragma unroll
    for (int c = 1; c < NCLS; ++c) rm = fmaxf(rm, cl[c]);
    float e[NCLS];
    float rs = 0.0f;
#pragma unroll
    for (int c = 0; c < NCLS; ++c) { e[c] = expf(cl[c] - rm); rs += e[c]; }
    const float inv = 1.0f / rs;

    __syncthreads();

#pragma unroll
    for (int c = 0; c < NCLS; ++c) {
        const float cp = e[c] * inv;
        const float op = expf(ob[c] - colmax[c]) / colsum[c];
        out[t * NCLS + c] = cp * op;
    }
}

// ---------------- launch ----------------------------------------------------
extern "C" void kernel_launch(void* const* d_in, const int* in_sizes, int n_in,
                              void* d_out, int out_size, void* d_ws, size_t ws_size,
                              hipStream_t stream) {
    const float* proposals = (const float*)d_in[0];  // (256,6)
    const float* xyz       = (const float*)d_in[1];  // (100000,3)
    const float* feats     = (const float*)d_in[2];  // (100000,256)
    const float* Wc        = (const float*)d_in[3];  // (256,21)
    const float* bc        = (const float*)d_in[4];  // (21)
    const float* Wo        = (const float*)d_in[5];  // (256,21)
    const float* bo        = (const float*)d_in[6];  // (21)
    float* out = (float*)d_out;                      // (256,21)

    char* ws = (char*)d_ws;
    u16t* fwb   = (u16t*)(ws);                       // 100000*48*2 = 9,600,000 B
    float* gacc = (float*)(ws + 9600000);            // 256*44*4    = 45,056 B
    u16t* bfrag = (u16t*)(ws + 9600000 + 45056);     // 24,576 B (64B-aligned)

    prep_kernel<<<1, 256, 0, stream>>>(Wc, Wo, bfrag, gacc);
    featw_kernel<<<FEATW_BLOCKS, 256, 0, stream>>>(feats, bfrag, fwb);
    roi_partial_kernel<<<P_PROP * NSEG, 256, 0, stream>>>(proposals, xyz, fwb, gacc);
    softmax_mul_kernel<<<1, 256, 0, stream>>>(gacc, bc, bo, out);
}